// Round 8
// baseline (1206.316 us; speedup 1.0000x reference)
//
#include <hip/hip_runtime.h>

#define NPIX 262144   // B*H*H = 4*256*256
#define M1C 4096
#define M2C 512
#define E1C 65536
#define E2C 8192
#define NBLK 512      // persistent grid: 2 blocks/CU on 256 CUs -> co-resident
#define NA 128        // group-A blocks (level-2 tail)
#define MROWS 4       // rows per block-iteration in fused MLP phases
#define TOTW (NPIX + M1C + E1C + E2C)

// ---- workspace layout (4-byte element offsets; ints and floats share the space) ----
// zeroed region: barrier counters + int histograms (memset'd every call):
constexpr int IOFF_BAR  = 0;                 // [0]=global barrier, [1]=groupA barrier
constexpr int IOFF_H1   = 4;                 // 4096
constexpr int IOFF_HC2  = IOFF_H1  + M1C;    // 512
constexpr int IOFF_HE1  = IOFF_HC2 + M2C;    // 4096
constexpr int IOFF_HE2  = IOFF_HE1 + M1C;    // 512
constexpr int ZEROI_END = IOFF_HE2 + M2C;    // 9220 ints

constexpr int IOFF_ST1   = ZEROI_END;              // 4097
constexpr int IOFF_CU1   = IOFF_ST1  + M1C + 1;    // 4096
constexpr int IOFF_STC2  = IOFF_CU1  + M1C;        // 513
constexpr int IOFF_CUC2  = IOFF_STC2 + M2C + 1;    // 512
constexpr int IOFF_STE1  = IOFF_CUC2 + M2C;        // 4097
constexpr int IOFF_CUE1  = IOFF_STE1 + M1C + 1;    // 4096
constexpr int IOFF_STE2  = IOFF_CUE1 + M1C;        // 513
constexpr int IOFF_CUE2  = IOFF_STE2 + M2C + 1;    // 512
constexpr int IOFF_PLIST = IOFF_CUE2 + M2C;        // 262144 (pixels sorted by cluster)
constexpr int IOFF_R2L   = IOFF_PLIST + NPIX;      // 4096
constexpr int IOFF_E1L   = IOFF_R2L + M1C;         // 65536
constexpr int IOFF_E2L   = IOFF_E1L + E1C;         // 8192
constexpr int IEND0      = IOFF_E2L + E2C;
constexpr int IEND       = (IEND0 + 3) & ~3;       // 16B-align the float region

// float scratch:
constexpr int OFF_S1CR  = IEND;                    // 4096*4 raw coord sums
constexpr int OFF_C1    = OFF_S1CR + M1C*4;        // 4096 counts
constexpr int OFF_X1CAT = OFF_C1 + M1C;            // 4096*68
constexpr int OFF_X1FC  = OFF_X1CAT + M1C*68;      // 4096*64
constexpr int OFF_X1    = OFF_X1FC + M1C*64;       // 4096*64
constexpr int OFF_X2CAT = OFF_X1 + M1C*64;         // 512*68
constexpr int OFF_X2FC  = OFF_X2CAT + M2C*68;      // 512*64
constexpr int OFF_X2    = OFF_X2FC + M2C*64;       // 512*64
constexpr int OFF_JSF1  = OFF_X2 + M2C*64;         // 4096*20
constexpr int OFF_JSF2  = OFF_JSF1 + M1C*20;       // 512*20

// ---------------- device-scope software barrier (monotonic counter, no reset race) ----------------
__device__ __forceinline__ void gbar(int* bar, int target) {
  __threadfence();                       // release: prior global writes visible device-wide
  __syncthreads();
  if (threadIdx.x == 0) {
    __hip_atomic_fetch_add(bar, 1, __ATOMIC_ACQ_REL, __HIP_MEMORY_SCOPE_AGENT);
    while (__hip_atomic_load(bar, __ATOMIC_ACQUIRE, __HIP_MEMORY_SCOPE_AGENT) < target)
      __builtin_amdgcn_s_sleep(1);
  }
  __syncthreads();
  __threadfence();                       // acquire: invalidate stale cached lines
}

// ---------------- 256-thread exclusive scan of N bins ----------------
template<int N>
__device__ __forceinline__ void scan256(const int* __restrict__ hist, int* __restrict__ start,
                                        int* __restrict__ curs, int* part, int tid) {
  constexpr int IT = N / 256;
  int base = tid * IT;
  int loc[IT];
  int sum = 0;
  #pragma unroll
  for (int k = 0; k < IT; ++k) { loc[k] = sum; sum += hist[base + k]; }
  part[tid] = sum;
  __syncthreads();
  for (int off = 1; off < 256; off <<= 1) {
    int v = (tid >= off) ? part[tid - off] : 0;
    __syncthreads();
    part[tid] += v;
    __syncthreads();
  }
  int excl = tid ? part[tid - 1] : 0;
  #pragma unroll
  for (int k = 0; k < IT; ++k) { start[base+k] = excl + loc[k]; curs[base+k] = excl + loc[k]; }
  if (tid == 255) start[N] = part[255];
  __syncthreads();
}

// ---------------- block-level dense layer (latency-optimized, LDS activations) ----------------
template<int NIN, int NOUT, int R, bool RELU>
__device__ __forceinline__ void block_layer(
    const float* __restrict__ W, const float* __restrict__ B,
    const float* __restrict__ actIn, float* __restrict__ actOut, int tid) {
  constexpr int NG  = 256 / NOUT;
  constexpr int RPT = (R + NG - 1) / NG;
  static_assert(NIN % 4 == 0, "NIN must be multiple of 4");
  int c  = tid % NOUT;
  int rg = tid / NOUT;
  if (rg < NG) {
    float acc[RPT];
    #pragma unroll
    for (int i = 0; i < RPT; ++i) acc[i] = 0.f;
    #pragma unroll 4
    for (int kc = 0; kc < NIN/4; ++kc) {
      float w0 = W[(kc*4+0)*NOUT + c];
      float w1 = W[(kc*4+1)*NOUT + c];
      float w2 = W[(kc*4+2)*NOUT + c];
      float w3 = W[(kc*4+3)*NOUT + c];
      #pragma unroll
      for (int i = 0; i < RPT; ++i) {
        int r = rg + i*NG;
        if (r < R) {
          float4 a = *reinterpret_cast<const float4*>(actIn + r*NIN + kc*4);
          acc[i] = fmaf(a.x, w0, fmaf(a.y, w1, fmaf(a.z, w2, fmaf(a.w, w3, acc[i]))));
        }
      }
    }
    float b = B[c];
    #pragma unroll
    for (int i = 0; i < RPT; ++i) {
      int r = rg + i*NG;
      if (r < R) {
        float v = acc[i] + b;
        actOut[r*NOUT + c] = RELU ? fmaxf(v, 0.f) : v;
      }
    }
  }
  __syncthreads();
}

// ---------------- t-MLP on 4 rows: 68 -> 100 -> 100 -> 100 -> 64 ----------------
__device__ __forceinline__ void mlp_t4(
    const float* __restrict__ X, const float* wi, const float* bi,
    const float* wh, const float* bh, const float* wo, const float* bo,
    float* __restrict__ Y, int r0, float* bufA, float* bufB, int tid) {
  for (int o = tid; o < MROWS*68; o += 256) bufA[o] = X[r0*68 + o];
  __syncthreads();
  block_layer<68,100,MROWS,true>(wi, bi, bufA, bufB, tid);
  block_layer<100,100,MROWS,true>(wh, bh, bufB, bufA, tid);
  block_layer<100,100,MROWS,true>(wh+10000, bh+100, bufA, bufB, tid);
  block_layer<100,64,MROWS,false>(wo, bo, bufB, bufA, tid);
  for (int o = tid; o < MROWS*64; o += 256) Y[r0*64 + o] = bufA[o];
  __syncthreads();
}

// ---------------- q-MLP on 4 rows: 64 -> 100^3 -> 18 (J stride 20) ----------------
__device__ __forceinline__ void mlp_q4(
    const float* __restrict__ X, const float* wi, const float* bi,
    const float* wh, const float* bh, const float* wo, const float* bo,
    float* __restrict__ J, int r0, float* bufA, float* bufB, int tid) {
  for (int o = tid; o < MROWS*64; o += 256) bufA[o] = X[r0*64 + o];
  __syncthreads();
  block_layer<64,100,MROWS,true>(wi, bi, bufA, bufB, tid);
  block_layer<100,100,MROWS,true>(wh, bh, bufB, bufA, tid);
  block_layer<100,100,MROWS,true>(wh+10000, bh+100, bufA, bufB, tid);
  block_layer<100,18,MROWS,false>(wo, bo, bufB, bufA, tid);
  for (int o = tid; o < MROWS*18; o += 256) {
    int r = o / 18, c = o - r*18;
    J[(r0+r)*20 + c] = bufA[o];
  }
  __syncthreads();
}

// ---------------- graph conv for one dst row, one wave (LDS region per wave) ----------------
__device__ __forceinline__ void gc_wave(
    const int* __restrict__ start, const int* __restrict__ elist, const float* __restrict__ xin,
    const float* wn, const float* wsf, const float* bias,
    float* __restrict__ xout, float* __restrict__ out_f, int d, int c, float* sm) {
  int p0 = start[d], p1 = start[d+1];
  float acc = 0.f;
  for (int p = p0; p < p1; ++p) acc += xin[elist[p]*64 + c];
  sm[c]      = acc / fmaxf((float)(p1 - p0), 1.0f);
  sm[64 + c] = xin[d*64 + c];
  __syncthreads();
  float o = bias[c];
  #pragma unroll 8
  for (int k = 0; k < 64; ++k)
    o += sm[k]*wn[k*64 + c] + sm[64 + k]*wsf[k*64 + c];
  xout[d*64 + c] = o;
  out_f[d*64 + c] = o;
  __syncthreads();
}

// ==================== the persistent mega-kernel ====================
__global__ __launch_bounds__(256, 2) void mega(
    const float* __restrict__ img, const float* __restrict__ cw, const float* __restrict__ cb,
    const float* t1_wi, const float* t1_bi, const float* t1_wh, const float* t1_bh,
    const float* t1_wo, const float* t1_bo,
    const float* t2_wi, const float* t2_bi, const float* t2_wh, const float* t2_bh,
    const float* t2_wo, const float* t2_bo,
    const float* q_wi, const float* q_bi, const float* q_wh, const float* q_bh,
    const float* q_wo, const float* q_bo,
    const float* gc1_wn, const float* gc1_ws, const float* gc1_b,
    const float* gc2_wn, const float* gc2_ws, const float* gc2_b,
    const int* __restrict__ cluster1, const int* __restrict__ cluster2,
    const int* __restrict__ e1, const int* __restrict__ e2,
    float* __restrict__ ws, float* __restrict__ o_r1, float* __restrict__ o_r2,
    float* __restrict__ o_x1, float* __restrict__ o_x2) {
  int* wsI = (int*)ws;
  int* bar  = wsI + IOFF_BAR;
  int* bar2 = wsI + IOFF_BAR + 1;
  int bid = blockIdx.x, tid = threadIdx.x;
  int gid = bid*256 + tid;
  int wv = tid >> 6, l = tid & 63;
  int wid = bid*4 + wv;                       // global wave id, 2048 waves

  __shared__ __align__(16) float bufA[MROWS*100];
  __shared__ __align__(16) float bufB[MROWS*100];
  __shared__ float smW[4*128];
  __shared__ int  part[256];

  // ---- P1: histograms ----
  for (int i = gid; i < TOTW; i += NBLK*256) {
    if (i < NPIX) {
      atomicAdd(&wsI[IOFF_H1 + cluster1[i]], 1);
    } else if (i < NPIX + M1C) {
      atomicAdd(&wsI[IOFF_HC2 + cluster2[i - NPIX]], 1);
    } else if (i < NPIX + M1C + E1C) {
      int e = i - NPIX - M1C;
      atomicAdd(&wsI[IOFF_HE1 + e1[E1C + e]], 1);
    } else {
      int e = i - NPIX - M1C - E1C;
      atomicAdd(&wsI[IOFF_HE2 + e2[E2C + e]], 1);
    }
  }
  gbar(bar, NBLK*1);

  // ---- P2: exclusive scans (blocks 0..3) ----
  if (bid == 0)      scan256<M1C>(wsI+IOFF_H1,  wsI+IOFF_ST1,  wsI+IOFF_CU1,  part, tid);
  else if (bid == 1) scan256<M2C>(wsI+IOFF_HC2, wsI+IOFF_STC2, wsI+IOFF_CUC2, part, tid);
  else if (bid == 2) scan256<M1C>(wsI+IOFF_HE1, wsI+IOFF_STE1, wsI+IOFF_CUE1, part, tid);
  else if (bid == 3) scan256<M2C>(wsI+IOFF_HE2, wsI+IOFF_STE2, wsI+IOFF_CUE2, part, tid);
  gbar(bar, NBLK*2);

  // ---- P3: scatter into bins ----
  for (int i = gid; i < TOTW; i += NBLK*256) {
    if (i < NPIX) {
      int s = cluster1[i];
      int pos = atomicAdd(&wsI[IOFF_CU1 + s], 1);
      wsI[IOFF_PLIST + pos] = i;
    } else if (i < NPIX + M1C) {
      int r = i - NPIX;
      int pos = atomicAdd(&wsI[IOFF_CUC2 + cluster2[r]], 1);
      wsI[IOFF_R2L + pos] = r;
    } else if (i < NPIX + M1C + E1C) {
      int e = i - NPIX - M1C;
      int pos = atomicAdd(&wsI[IOFF_CUE1 + e1[E1C + e]], 1);
      wsI[IOFF_E1L + pos] = e1[e];
    } else {
      int e = i - NPIX - M1C - E1C;
      int pos = atomicAdd(&wsI[IOFF_CUE2 + e2[E2C + e]], 1);
      wsI[IOFF_E2L + pos] = e2[e];
    }
  }
  gbar(bar, NBLK*3);

  // ---- P4: conv-linearity cluster gather (wave per cluster, 2 clusters/wave) ----
  {
    const int* startp = wsI + IOFF_ST1;
    const int* plist  = wsI + IOFF_PLIST;
    for (int s = wid; s < M1C; s += 2048) {
      int p0 = startp[s], p1 = startp[s+1];
      int count = p1 - p0;
      float ps[27];
      #pragma unroll
      for (int k = 0; k < 27; ++k) ps[k] = 0.f;
      float sy = 0.f, sx = 0.f, syy = 0.f, sxx = 0.f;
      for (int p = p0 + l; p < p1; p += 64) {
        int n = plist[p];
        int b = n >> 16, pp = n & 65535, i = pp >> 8, j = pp & 255;
        #pragma unroll
        for (int di = 0; di < 3; ++di) {
          int y = i + di - 1;
          #pragma unroll
          for (int dj = 0; dj < 3; ++dj) {
            int x = j + dj - 1;
            int k = (di*3 + dj)*3;
            if ((unsigned)y < 256u && (unsigned)x < 256u) {
              int base = ((b << 16) + (y << 8) + x) * 3;
              ps[k+0] += img[base];
              ps[k+1] += img[base+1];
              ps[k+2] += img[base+2];
            }
          }
        }
        float yi = i * (1.0f/256.0f), xj = j * (1.0f/256.0f);
        sy += yi; sx += xj; syy += yi*yi; sxx += xj*xj;
      }
      #pragma unroll
      for (int m = 1; m < 64; m <<= 1) {
        #pragma unroll
        for (int k = 0; k < 27; ++k) ps[k] += __shfl_xor(ps[k], m);
        sy  += __shfl_xor(sy,  m);
        sx  += __shfl_xor(sx,  m);
        syy += __shfl_xor(syy, m);
        sxx += __shfl_xor(sxx, m);
      }
      float inv = 1.0f / fmaxf((float)count, 1.0f);
      float o = cb[l];
      #pragma unroll
      for (int k = 0; k < 27; ++k) o = fmaf(ps[k]*inv, cw[k*64 + l], o);
      ws[OFF_X1CAT + s*68 + l] = count ? o : 0.f;
      if (l == 0) {
        ws[OFF_X1CAT + s*68 + 64] = sy*inv;
        ws[OFF_X1CAT + s*68 + 65] = sx*inv;
        ws[OFF_X1CAT + s*68 + 66] = syy*inv;
        ws[OFF_X1CAT + s*68 + 67] = sxx*inv;
        ws[OFF_S1CR + s*4+0] = sy; ws[OFF_S1CR + s*4+1] = sx;
        ws[OFF_S1CR + s*4+2] = syy; ws[OFF_S1CR + s*4+3] = sxx;
        ws[OFF_JSF1 + s*20 + 18] = sy*inv;
        ws[OFF_JSF1 + s*20 + 19] = sx*inv;
        ws[OFF_C1 + s] = (float)count;
      }
    }
  }
  gbar(bar, NBLK*4);

  // ---- P5: t1 MLP (1024 row-blocks over 512 blocks) ----
  for (int rb = bid; rb < M1C/MROWS; rb += NBLK)
    mlp_t4(ws+OFF_X1CAT, t1_wi, t1_bi, t1_wh, t1_bh, t1_wo, t1_bo,
           ws+OFF_X1FC, rb*MROWS, bufA, bufB, tid);
  gbar(bar, NBLK*5);

  // ---- P6: graph conv 1 (wave per dst, 2 dst/wave) ----
  for (int d = wid; d < M1C; d += 2048)
    gc_wave(wsI+IOFF_STE1, wsI+IOFF_E1L, ws+OFF_X1FC,
            gc1_wn, gc1_ws, gc1_b, ws+OFF_X1, o_x1, d, l, smW + wv*128);
  gbar(bar, NBLK*6);

  // ---- split: group A (bid<NA) does the level-2 tail; group B does q-MLP on x1 ----
  if (bid < NA) {
    // A1: pool_l2 (wave per cluster, 512 waves exact)
    {
      int s2 = wid;                               // wid < 512 for bid < 128
      const int* startc2 = wsI + IOFF_STC2;
      const int* r2list  = wsI + IOFF_R2L;
      int p0 = startc2[s2], p1 = startc2[s2+1];
      int k = l & 3;
      float acc = 0.f, sc = 0.f, cnt = 0.f;
      for (int p = p0; p < p1; ++p) {
        int r = r2list[p];
        acc += ws[OFF_X1 + r*64 + l];
        sc  += ws[OFF_S1CR + r*4 + k];
        cnt += ws[OFF_C1 + r];
      }
      float invr = 1.0f / fmaxf((float)(p1 - p0), 1.0f);
      ws[OFF_X2CAT + s2*68 + l] = acc * invr;
      if (l < 4) {
        float mean = sc / fmaxf(cnt, 1.0f);
        ws[OFF_X2CAT + s2*68 + 64 + l] = mean;
        if (l == 0) ws[OFF_JSF2 + s2*20 + 18] = mean;
        if (l == 1) ws[OFF_JSF2 + s2*20 + 19] = mean;
      }
    }
    gbar(bar2, NA*1);
    // A2: t2 MLP (128 row-blocks exact)
    mlp_t4(ws+OFF_X2CAT, t2_wi, t2_bi, t2_wh, t2_bh, t2_wo, t2_bo,
           ws+OFF_X2FC, bid*MROWS, bufA, bufB, tid);
    gbar(bar2, NA*2);
    // A3: graph conv 2 (512 waves exact)
    gc_wave(wsI+IOFF_STE2, wsI+IOFF_E2L, ws+OFF_X2FC,
            gc2_wn, gc2_ws, gc2_b, ws+OFF_X2, o_x2, wid, l, smW + wv*128);
    gbar(bar2, NA*3);
    // A4: q MLP on x2 rows (128 row-blocks exact)
    mlp_q4(ws+OFF_X2, q_wi, q_bi, q_wh, q_bh, q_wo, q_bo,
           ws+OFF_JSF2, bid*MROWS, bufA, bufB, tid);
  } else {
    // B: q MLP on x1 rows (1024 row-blocks over 384 blocks)
    for (int rb = bid - NA; rb < M1C/MROWS; rb += (NBLK - NA))
      mlp_q4(ws+OFF_X1, q_wi, q_bi, q_wh, q_bh, q_wo, q_bo,
             ws+OFF_JSF1, rb*MROWS, bufA, bufB, tid);
  }
  gbar(bar, NBLK*7);

  // ---- P8: render ----
  for (int n = gid; n < NPIX; n += NBLK*256) {
    int p = n & 65535, i = p >> 8, j = p & 255;
    float gy = i * (1.0f/256.0f), gx = j * (1.0f/256.0f);
    int s = cluster1[n];
    {
      const float4* f4 = reinterpret_cast<const float4*>(ws + OFF_JSF1 + s*20);
      float4 v0 = f4[0], v1 = f4[1], v2 = f4[2], v3 = f4[3], v4 = f4[4];
      float dx = gy - v0.x, dy = gx - v0.y;
      float dxx = dx*dx, dyy = dy*dy, dxy = dx*dy;
      o_r1[n*3 + 0] = v0.z + v0.w*dx + v1.x*dy + v1.y*dxx + v1.z*dyy + v1.w*dxy;
      o_r1[n*3 + 1] = v2.x + v2.y*dx + v2.z*dy + v2.w*dxx + v3.x*dyy + v3.y*dxy;
      o_r1[n*3 + 2] = v3.z + v3.w*dx + v4.x*dy + v4.y*dxx + v4.z*dyy + v4.w*dxy;
    }
    int s2 = cluster2[s];
    {
      const float4* f4 = reinterpret_cast<const float4*>(ws + OFF_JSF2 + s2*20);
      float4 v0 = f4[0], v1 = f4[1], v2 = f4[2], v3 = f4[3], v4 = f4[4];
      float dx = gy - v0.x, dy = gx - v0.y;
      float dxx = dx*dx, dyy = dy*dy, dxy = dx*dy;
      o_r2[n*3 + 0] = v0.z + v0.w*dx + v1.x*dy + v1.y*dxx + v1.z*dyy + v1.w*dxy;
      o_r2[n*3 + 1] = v2.x + v2.y*dx + v2.z*dy + v2.w*dxx + v3.x*dyy + v3.y*dxy;
      o_r2[n*3 + 2] = v3.z + v3.w*dx + v4.x*dy + v4.y*dxx + v4.z*dyy + v4.w*dxy;
    }
  }
}

extern "C" void kernel_launch(void* const* d_in, const int* in_sizes, int n_in,
                              void* d_out, int out_size, void* d_ws, size_t ws_size,
                              hipStream_t stream) {
  const float* img    = (const float*)d_in[0];
  const float* conv_w = (const float*)d_in[1];
  const float* conv_b = (const float*)d_in[2];
  const float* t1_wi = (const float*)d_in[3];  const float* t1_bi = (const float*)d_in[4];
  const float* t1_wh = (const float*)d_in[5];  const float* t1_bh = (const float*)d_in[6];
  const float* t1_wo = (const float*)d_in[7];  const float* t1_bo = (const float*)d_in[8];
  const float* t2_wi = (const float*)d_in[9];  const float* t2_bi = (const float*)d_in[10];
  const float* t2_wh = (const float*)d_in[11]; const float* t2_bh = (const float*)d_in[12];
  const float* t2_wo = (const float*)d_in[13]; const float* t2_bo = (const float*)d_in[14];
  const float* q_wi  = (const float*)d_in[15]; const float* q_bi  = (const float*)d_in[16];
  const float* q_wh  = (const float*)d_in[17]; const float* q_bh  = (const float*)d_in[18];
  const float* q_wo  = (const float*)d_in[19]; const float* q_bo  = (const float*)d_in[20];
  const float* gc1_wn = (const float*)d_in[21]; const float* gc1_ws = (const float*)d_in[22];
  const float* gc1_b  = (const float*)d_in[23];
  const float* gc2_wn = (const float*)d_in[24]; const float* gc2_ws = (const float*)d_in[25];
  const float* gc2_b  = (const float*)d_in[26];
  const int* cluster1 = (const int*)d_in[27];
  const int* cluster2 = (const int*)d_in[28];
  const int* edges1   = (const int*)d_in[29];
  const int* edges2   = (const int*)d_in[30];

  float* ws = (float*)d_ws;
  float* out  = (float*)d_out;
  float* o_r1 = out;
  float* o_r2 = out + 786432;
  float* o_x1 = out + 1572864;
  float* o_x2 = out + 1835008;

  // zero barrier counters + int histograms (37 KB)
  hipMemsetAsync(d_ws, 0, (size_t)ZEROI_END * sizeof(int), stream);

  mega<<<NBLK, 256, 0, stream>>>(
      img, conv_w, conv_b,
      t1_wi, t1_bi, t1_wh, t1_bh, t1_wo, t1_bo,
      t2_wi, t2_bi, t2_wh, t2_bh, t2_wo, t2_bo,
      q_wi, q_bi, q_wh, q_bh, q_wo, q_bo,
      gc1_wn, gc1_ws, gc1_b, gc2_wn, gc2_ws, gc2_b,
      cluster1, cluster2, edges1, edges2,
      ws, o_r1, o_r2, o_x1, o_x2);
}